// Round 3
// baseline (445.003 us; speedup 1.0000x reference)
//
#include <hip/hip_runtime.h>
#include <cstdint>
#include <cstddef>

#define IN_F 4096
#define OUT_F 4096
#define RANKK 16
#define EPSQ 1e-8f
#define LSCALE 0.01f

typedef __attribute__((ext_vector_type(4))) int i32x4;
typedef __attribute__((ext_vector_type(16))) int i32x16;

__device__ __forceinline__ float quantf(float v, float s) {
    float q = rintf(v / s);             // RNE, matches jnp.round
    return fminf(7.f, fmaxf(-8.f, q));
}

// ---------------------------------------------------------------------------
// Kernel 1: quantize activations x -> int8 in [-8,7].  4 elems/thread.
// ---------------------------------------------------------------------------
__global__ __launch_bounds__(256) void qx_kernel(const float* __restrict__ x,
                                                 const float* __restrict__ ascale,
                                                 int8_t* __restrict__ qx) {
    const float asc = fmaxf(fabsf(ascale[0]), EPSQ);
    const int i = blockIdx.x * 256 + threadIdx.x;
    float4 v = ((const float4*)x)[i];
    union { int8_t b[4]; int w; } u;
    u.b[0] = (int8_t)(int)quantf(v.x, asc);
    u.b[1] = (int8_t)(int)quantf(v.y, asc);
    u.b[2] = (int8_t)(int)quantf(v.z, asc);
    u.b[3] = (int8_t)(int)quantf(v.w, asc);
    ((int*)qx)[i] = u.w;
}

// ---------------------------------------------------------------------------
// Kernel 2: merged = W + 0.01 * (lora_B @ lora_A); quantize per output row.
// ---------------------------------------------------------------------------
__global__ __launch_bounds__(256) void qw_kernel(const float* __restrict__ W,
                                                 const float* __restrict__ lA,
                                                 const float* __restrict__ lB,
                                                 const float* __restrict__ wscale,
                                                 int8_t* __restrict__ qw) {
    __shared__ float Ablk[RANKK][256];   // 16 KB
    __shared__ float Bblk[64][RANKK];    // 4 KB
    const int tid = threadIdx.x;
    const int i0 = blockIdx.x * 256;
    const int o0 = blockIdx.y * 64;

#pragma unroll
    for (int r = 0; r < RANKK; ++r)
        Ablk[r][tid] = lA[r * IN_F + i0 + tid];
    for (int j = tid; j < 64 * RANKK; j += 256)
        Bblk[j >> 4][j & 15] = lB[(size_t)(o0 + (j >> 4)) * RANKK + (j & 15)];
    __syncthreads();

    const int i = i0 + tid;
#pragma unroll 4
    for (int o = 0; o < 64; ++o) {
        float s = 0.f;
#pragma unroll
        for (int r = 0; r < RANKK; ++r) s += Bblk[o][r] * Ablk[r][tid];
        float merged = W[(size_t)(o0 + o) * IN_F + i] + LSCALE * s;
        float wsc = fmaxf(fabsf(wscale[o0 + o]), EPSQ);
        qw[(size_t)(o0 + o) * IN_F + i] = (int8_t)(int)quantf(merged, wsc);
    }
}

// ---------------------------------------------------------------------------
// Kernel 3: int8 GEMM.
//   Round-2 post-mortem: 1 block/CU with all-wave barriers ran the LDS pipe
//   (~3100 cyc/tile) and MFMA pipe (~2340 cyc/tile) SERIALIZED (sum matched
//   the measured 6563 cyc/tile).  The 154 µs baseline was faster because its
//   2 independent blocks/CU overlapped the pipes for free (m114).
//   This round: 2 blocks/CU (cross-block overlap) + double-buffer with
//   counted vmcnt (no latency drain) + conflict-free fragment-read swizzle.
//   BM=128, BN=256, BK=64, 256 thr / 4 waves (wave tile 64x128),
//   LDS 2 x (8K A + 16K B) = 48 KB/block -> 2 blocks/CU.
//   Per tile: { stage t+1 (6 x global_load_lds dwordx4);
//               s_waitcnt vmcnt(6)  <- waits ONLY tile-t's loads, issued one
//                                      full tile (~1200 cyc) earlier;
//               s_barrier (cross-wave visibility: every wave passed its own
//                          vmcnt, so all tile-t loads landed);
//               compute (2 kk x {6 ds_read_b128 + 8 MFMA});
//               s_barrier (all reads of buf done before it is restaged) }.
//   Swizzle (both-sides, rule #21): 64-B rows = 4 chunks of 16 B.  LDS slot
//   p (16 B) holds global chunk (row m = p>>2, chunk q = (p&3) ^ ((m>>1)&3));
//   fragment reads use slot = q ^ ((r>>1)&3).  Bank position of row r, fixed
//   q is determined by the PAIR (r&1, (r>>1)&3) — a bijection on r&7 — so
//   each 16-lane quarter-wave covers 8 bank positions exactly 2x
//   (2-way = free, m136), vs the old r&7-XOR's 4-way aliasing.
// ---------------------------------------------------------------------------
constexpr int BM = 128, BN = 256, BK = 64, KD = 4096, NT = KD / BK;  // 64

__device__ __forceinline__ void gll16(const int8_t* g, const int8_t* l) {
    __builtin_amdgcn_global_load_lds(
        (const __attribute__((address_space(1))) void*)g,
        (__attribute__((address_space(3))) void*)l, 16, 0, 0);
}

__global__ __launch_bounds__(256, 2) void gemm_i8_kernel(
        const int8_t* __restrict__ qx, const int8_t* __restrict__ qw,
        const float* __restrict__ wscale, const float* __restrict__ ascale,
        const float* __restrict__ bias, float* __restrict__ out) {
    __shared__ __attribute__((aligned(16))) int8_t As[2][BM * BK];  // 2x8 KB
    __shared__ __attribute__((aligned(16))) int8_t Bs[2][BN * BK];  // 2x16 KB

    const int tid  = threadIdx.x;
    const int lane = tid & 63;
    const int wave = tid >> 6;
    const int hi   = lane >> 5;

    // T1: XCD-aware swizzle.  nwg = 1024, % 8 == 0 -> bijective.
    const int bid  = blockIdx.x;
    const int swz  = (bid & 7) * 128 + (bid >> 3);
    const int m_tile = (swz >> 4) * BM;   // 64 M-tiles
    const int n_tile = (swz & 15) * BN;   // 16 N-tiles

    const int wm = (wave >> 1) * 64;      // wave M offset (0 or 64)
    const int wn = (wave & 1) * 128;      // wave N offset (0 or 128)

    // ---- staging: pre-swizzled global source offsets.
    // chunk p = is*256 + tid; row m = p>>2; LDS slot p&3 holds global
    // chunk q = (p&3) ^ ((m>>1)&3)  [(p>>3)&3 == (m>>1)&3].
    int srcA[2], srcB[4];
#pragma unroll
    for (int is = 0; is < 2; ++is) {
        int p = is * 256 + tid;
        srcA[is] = (p >> 2) * KD + ((((p & 3) ^ ((p >> 3) & 3))) << 4);
    }
#pragma unroll
    for (int is = 0; is < 4; ++is) {
        int p = is * 256 + tid;
        srcB[is] = (p >> 2) * KD + ((((p & 3) ^ ((p >> 3) & 3))) << 4);
    }
    const int lds_u = wave * 1024;        // wave-uniform LDS base component

    // ---- fragment read bases: row r, chunk q = kk*2 + hi,
    // slot = q ^ ((r>>1)&3);  addr = r*64 + slot*16.
    int aB[2], aH[2], bB[4], bH[4];
#pragma unroll
    for (int mi = 0; mi < 2; ++mi) {
        const int ra = wm + mi * 32 + (lane & 31);
        aB[mi] = ra * BK;
        aH[mi] = (ra >> 1) & 3;
    }
#pragma unroll
    for (int ni = 0; ni < 4; ++ni) {
        const int rb = wn + ni * 32 + (lane & 31);
        bB[ni] = rb * BK;
        bH[ni] = (rb >> 1) & 3;
    }

    const int8_t* Ab = qx + (size_t)m_tile * KD;
    const int8_t* Bb = qw + (size_t)n_tile * KD;

    i32x16 acc[2][4];
#pragma unroll
    for (int mi = 0; mi < 2; ++mi)
#pragma unroll
        for (int ni = 0; ni < 4; ++ni) acc[mi][ni] = (i32x16)(0);

    // ---- prologue: stage K-tile 0 into buffer 0 (A then B; 6 loads).
#pragma unroll
    for (int is = 0; is < 2; ++is)
        gll16(Ab + srcA[is], &As[0][is * 4096 + lds_u]);
#pragma unroll
    for (int is = 0; is < 4; ++is)
        gll16(Bb + srcB[is], &Bs[0][is * 4096 + lds_u]);

    for (int t = 0; t < NT; ++t) {
        const int buf = t & 1;
        // ---- stage tile t+1 into buf^1, then counted wait on tile t's 6
        // loads (issued one full tile earlier; prologue stall happens once).
        if (t + 1 < NT) {
            const int k1 = (t + 1) * BK;
            int8_t* dA = (int8_t*)As[buf ^ 1];
            int8_t* dB = (int8_t*)Bs[buf ^ 1];
#pragma unroll
            for (int is = 0; is < 2; ++is)
                gll16(Ab + k1 + srcA[is], dA + is * 4096 + lds_u);
#pragma unroll
            for (int is = 0; is < 4; ++is)
                gll16(Bb + k1 + srcB[is], dB + is * 4096 + lds_u);
            asm volatile("s_waitcnt vmcnt(6)" ::: "memory");
        } else {
            asm volatile("s_waitcnt vmcnt(0)" ::: "memory");
        }
        // barrier #1: every wave passed its own vmcnt -> all tile-t loads
        // from all waves have landed in LDS.
        asm volatile("s_barrier" ::: "memory");

        // ---- compute tile t: 2 kk steps x {6 ds_read_b128 + 8 MFMAs}.
        const int8_t* Asb = As[buf];
        const int8_t* Bsb = Bs[buf];
#pragma unroll
        for (int kk = 0; kk < 2; ++kk) {
            const int q = kk * 2 + hi;
            i32x4 af[2], bf[4];
#pragma unroll
            for (int mi = 0; mi < 2; ++mi)
                af[mi] = *(const i32x4*)(Asb + aB[mi] + ((q ^ aH[mi]) << 4));
#pragma unroll
            for (int ni = 0; ni < 4; ++ni)
                bf[ni] = *(const i32x4*)(Bsb + bB[ni] + ((q ^ bH[ni]) << 4));
            __builtin_amdgcn_s_setprio(1);
#pragma unroll
            for (int mi = 0; mi < 2; ++mi)
#pragma unroll
                for (int ni = 0; ni < 4; ++ni)
                    acc[mi][ni] = __builtin_amdgcn_mfma_i32_32x32x32_i8(
                        af[mi], bf[ni], acc[mi][ni], 0, 0, 0);
            __builtin_amdgcn_s_setprio(0);
        }
        // barrier #2: all waves done reading buf before iteration t+1
        // restages it (t+2 goes into buf[(t+2)&1] == buf).
        asm volatile("s_barrier" ::: "memory");
    }

    // ---- epilogue.  C/D layout: col = lane&31, row = (r&3)+8*(r>>2)+4*hi.
    const float asc = fmaxf(fabsf(ascale[0]), EPSQ);
#pragma unroll
    for (int ni = 0; ni < 4; ++ni) {
        const int n  = n_tile + wn + ni * 32 + (lane & 31);
        const float sc = asc * fmaxf(fabsf(wscale[n]), EPSQ);
        const float bb = bias[n];
#pragma unroll
        for (int mi = 0; mi < 2; ++mi) {
            const int rbase = m_tile + wm + mi * 32 + 4 * hi;
#pragma unroll
            for (int r = 0; r < 16; ++r) {
                const int row = rbase + (r & 3) + 8 * (r >> 2);
                out[(size_t)row * OUT_F + n] = sc * (float)acc[mi][ni][r] + bb;
            }
        }
    }
}

// ---------------------------------------------------------------------------
extern "C" void kernel_launch(void* const* d_in, const int* in_sizes, int n_in,
                              void* d_out, int out_size, void* d_ws, size_t ws_size,
                              hipStream_t stream) {
    const float* x      = (const float*)d_in[0];
    const float* W      = (const float*)d_in[1];
    const float* lA     = (const float*)d_in[2];
    const float* lB     = (const float*)d_in[3];
    const float* wscale = (const float*)d_in[4];
    const float* ascale = (const float*)d_in[5];
    const float* bias   = (const float*)d_in[6];
    float* out = (float*)d_out;

    const int M = in_sizes[0] / IN_F;          // 8192
    int8_t* qx = (int8_t*)d_ws;                             // M*K bytes
    int8_t* qw = qx + (size_t)M * IN_F;                     // N*K bytes

    qx_kernel<<<(in_sizes[0] / 4 + 255) / 256, 256, 0, stream>>>(x, ascale, qx);
    qw_kernel<<<dim3(IN_F / 256, OUT_F / 64), 256, 0, stream>>>(W, lA, lB, wscale, qw);
    gemm_i8_kernel<<<dim3((M / BM) * (OUT_F / BN)), 256, 0, stream>>>(
        qx, qw, wscale, ascale, bias, out);
}

// Round 5
// 443.931 us; speedup vs baseline: 1.0024x; 1.0024x over previous
//
#include <hip/hip_runtime.h>
#include <cstdint>
#include <cstddef>

#define IN_F 4096
#define OUT_F 4096
#define RANKK 16
#define EPSQ 1e-8f
#define LSCALE 0.01f

typedef __attribute__((ext_vector_type(4))) int i32x4;
typedef __attribute__((ext_vector_type(16))) int i32x16;

__device__ __forceinline__ float quantm(float v, float sinv) {
    float q = rintf(v * sinv);          // hoisted reciprocal; ulp-level diff
    return fminf(7.f, fmaxf(-8.f, q));  // absorbed by quant tolerance
}

// ---------------------------------------------------------------------------
// Kernel 1: quantize activations x -> int8.  8 elems/thread (two float4
// loads, one int2 store = 8 B/lane, G13 sweet spot); reciprocal hoisted.
// ---------------------------------------------------------------------------
__global__ __launch_bounds__(256) void qx_kernel(const float* __restrict__ x,
                                                 const float* __restrict__ ascale,
                                                 int8_t* __restrict__ qx) {
    const float asc  = fmaxf(fabsf(ascale[0]), EPSQ);
    const float ainv = 1.f / asc;
    const long i = (long)blockIdx.x * 256 + threadIdx.x;
    float4 v0 = ((const float4*)x)[2 * i];
    float4 v1 = ((const float4*)x)[2 * i + 1];
    union { int8_t b[8]; int2 w; } u;
    u.b[0] = (int8_t)(int)quantm(v0.x, ainv);
    u.b[1] = (int8_t)(int)quantm(v0.y, ainv);
    u.b[2] = (int8_t)(int)quantm(v0.z, ainv);
    u.b[3] = (int8_t)(int)quantm(v0.w, ainv);
    u.b[4] = (int8_t)(int)quantm(v1.x, ainv);
    u.b[5] = (int8_t)(int)quantm(v1.y, ainv);
    u.b[6] = (int8_t)(int)quantm(v1.z, ainv);
    u.b[7] = (int8_t)(int)quantm(v1.w, ainv);
    ((int2*)qx)[i] = u.w;
}

// ---------------------------------------------------------------------------
// Kernel 2: merged = W + 0.01 * (lora_B @ lora_A); quantize per output row.
// Thread owns 4 consecutive i (float4 W/A loads, int stores = 4 B/lane vs
// old 1 B/lane).  Block = 1024 i x 64 o.  A in 64 VGPRs, B (4 KB) in LDS
// with broadcast reads (no conflicts).
// ---------------------------------------------------------------------------
__global__ __launch_bounds__(256) void qw_kernel(const float* __restrict__ W,
                                                 const float* __restrict__ lA,
                                                 const float* __restrict__ lB,
                                                 const float* __restrict__ wscale,
                                                 int8_t* __restrict__ qw) {
    __shared__ float Bblk[64][RANKK];    // 4 KB
    const int tid = threadIdx.x;
    const int i0 = blockIdx.x * 1024;
    const int o0 = blockIdx.y * 64;

    {   // stage B: 1024 floats, one float4/thread, coalesced.
        float4 b4 = ((const float4*)(lB + (size_t)o0 * RANKK))[tid];
        *(float4*)&Bblk[tid >> 2][(tid & 3) * 4] = b4;
    }
    const int i = i0 + tid * 4;
    float4 a[RANKK];
#pragma unroll
    for (int r = 0; r < RANKK; ++r)
        a[r] = *(const float4*)(lA + (size_t)r * IN_F + i);
    __syncthreads();

#pragma unroll 4
    for (int o = 0; o < 64; ++o) {
        const float4 w = *(const float4*)(W + (size_t)(o0 + o) * IN_F + i);
        float sx = 0.f, sy = 0.f, sz = 0.f, sw = 0.f;
#pragma unroll
        for (int r = 0; r < RANKK; ++r) {
            const float b = Bblk[o][r];
            sx += b * a[r].x; sy += b * a[r].y;
            sz += b * a[r].z; sw += b * a[r].w;
        }
        const float wsc  = fmaxf(fabsf(wscale[o0 + o]), EPSQ);
        const float winv = 1.f / wsc;
        union { int8_t b[4]; int w; } u;
        u.b[0] = (int8_t)(int)quantm(w.x + LSCALE * sx, winv);
        u.b[1] = (int8_t)(int)quantm(w.y + LSCALE * sy, winv);
        u.b[2] = (int8_t)(int)quantm(w.z + LSCALE * sz, winv);
        u.b[3] = (int8_t)(int)quantm(w.w + LSCALE * sw, winv);
        *(int*)(qw + (size_t)(o0 + o) * IN_F + i) = u.w;
    }
}

// ---------------------------------------------------------------------------
// Kernel 3: int8 GEMM — 16 waves/CU via small register footprint.
//   Key insight (round-4 audit): occupancy is capped by COMBINED VGPR+AGPR
//   (gfx950 unified file).  Old 64x128 wave tile = 128 AGPR acc + ~100 VGPR
//   = 228 regs -> 2 waves/SIMD, 8 waves/CU (the measured 20% ceiling across
//   ALL prior rounds, independent of LDS/schedule).  To test the
//   phase-diversity theory (m114) at all, the wave tile must shrink.
//   Config: BM=BN=128, BK=128, 4 waves (2x2), wave tile 64x64:
//   acc = 4 x i32x16 = 64 AGPR; total ~120 regs -> 4 waves/SIMD.
//   LDS 16K A + 16K B = 32 KB single-buffer -> 4 blocks/CU (grid 2048 =
//   8/CU, two rounds, zero tail).  Per-tile vmcnt(0) drain de-phases
//   against 3 other blocks' MFMA bursts.
//   Staging + swizzle + fragment reads: byte-identical to the round-0
//   PROVEN 128-row/BK=128 pattern (slot c = q ^ (row&7)), applied to both
//   A and B.  Bank conflicts are intrinsic ~4 cyc/ds_read_b128 (proven
//   invariant across 3 swizzle schemes) — not a target.
// ---------------------------------------------------------------------------
constexpr int BM = 128, BN = 128, BK = 128, KD = 4096, NT = KD / BK;  // 32

__device__ __forceinline__ void gll16(const int8_t* g, const int8_t* l) {
    __builtin_amdgcn_global_load_lds(
        (const __attribute__((address_space(1))) void*)g,
        (__attribute__((address_space(3))) void*)l, 16, 0, 0);
}

__global__ __launch_bounds__(256, 4) void gemm_i8_kernel(
        const int8_t* __restrict__ qx, const int8_t* __restrict__ qw,
        const float* __restrict__ wscale, const float* __restrict__ ascale,
        const float* __restrict__ bias, float* __restrict__ out) {
    __shared__ __attribute__((aligned(16))) int8_t As[BM * BK];  // 16 KB
    __shared__ __attribute__((aligned(16))) int8_t Bs[BN * BK];  // 16 KB

    const int tid  = threadIdx.x;
    const int lane = tid & 63;
    const int wave = tid >> 6;
    const int hi   = lane >> 5;

    // T1: XCD-aware swizzle.  nwg = 2048, % 8 == 0 -> bijective.
    const int bid  = blockIdx.x;
    const int swz  = (bid & 7) * 256 + (bid >> 3);
    const int m_tile = (swz >> 5) * BM;   // 64 M-tiles
    const int n_tile = (swz & 31) * BN;   // 32 N-tiles

    const int wm = (wave >> 1) * 64;      // wave M offset (0 or 64)
    const int wn = (wave & 1) * 64;       // wave N offset (0 or 64)

    // ---- staging: pre-swizzled global source offsets (A and B identical:
    // 128 rows x 128 B = 1024 chunks = 4 instr x 256 thr).
    // chunk p = is*256 + tid; row m = p>>3; LDS slot p&7 holds global
    // chunk q = (p&7) ^ (m&7).
    int src[4];
#pragma unroll
    for (int is = 0; is < 4; ++is) {
        int p = is * 256 + tid;
        int m = p >> 3;
        src[is] = m * KD + (((p & 7) ^ (m & 7)) << 4);
    }
    const int lds_u = wave * 1024;        // wave-uniform LDS base component

    // ---- fragment read bases: row r, chunk q = kk*2 + hi, slot = q^(r&7).
    int aB[2], aH[2], bB[2], bH[2];
#pragma unroll
    for (int mi = 0; mi < 2; ++mi) {
        const int ra = wm + mi * 32 + (lane & 31);
        aB[mi] = ra * BK;
        aH[mi] = ra & 7;
    }
#pragma unroll
    for (int ni = 0; ni < 2; ++ni) {
        const int rb = wn + ni * 32 + (lane & 31);
        bB[ni] = rb * BK;
        bH[ni] = rb & 7;
    }

    const int8_t* Ab = qx + (size_t)m_tile * KD;
    const int8_t* Bb = qw + (size_t)n_tile * KD;

    i32x16 acc[2][2];
#pragma unroll
    for (int mi = 0; mi < 2; ++mi)
#pragma unroll
        for (int ni = 0; ni < 2; ++ni) acc[mi][ni] = (i32x16)(0);

    for (int t = 0; t < NT; ++t) {
        const int k0 = t * BK;
        // ---- stage tile t (single buffer, 8 x global_load_lds dwordx4).
#pragma unroll
        for (int is = 0; is < 4; ++is)
            gll16(Ab + k0 + src[is], &As[is * 4096 + lds_u]);
#pragma unroll
        for (int is = 0; is < 4; ++is)
            gll16(Bb + k0 + src[is], &Bs[is * 4096 + lds_u]);
        // implicit vmcnt(0) drain at the barrier — hidden by the other 3
        // resident blocks' compute (the experiment of this round).
        __syncthreads();

        // ---- compute tile t: 4 kk steps x {4 ds_read_b128 + 4 MFMAs}.
#pragma unroll
        for (int kk = 0; kk < 4; ++kk) {
            const int q = kk * 2 + hi;
            i32x4 af[2], bf[2];
#pragma unroll
            for (int mi = 0; mi < 2; ++mi)
                af[mi] = *(const i32x4*)(As + aB[mi] + ((q ^ aH[mi]) << 4));
#pragma unroll
            for (int ni = 0; ni < 2; ++ni)
                bf[ni] = *(const i32x4*)(Bs + bB[ni] + ((q ^ bH[ni]) << 4));
            __builtin_amdgcn_s_setprio(1);
#pragma unroll
            for (int mi = 0; mi < 2; ++mi)
#pragma unroll
                for (int ni = 0; ni < 2; ++ni)
                    acc[mi][ni] = __builtin_amdgcn_mfma_i32_32x32x32_i8(
                        af[mi], bf[ni], acc[mi][ni], 0, 0, 0);
            __builtin_amdgcn_s_setprio(0);
        }
        __syncthreads();
    }

    // ---- epilogue.  C/D layout: col = lane&31, row = (r&3)+8*(r>>2)+4*hi.
    const float asc = fmaxf(fabsf(ascale[0]), EPSQ);
#pragma unroll
    for (int ni = 0; ni < 2; ++ni) {
        const int n  = n_tile + wn + ni * 32 + (lane & 31);
        const float sc = asc * fmaxf(fabsf(wscale[n]), EPSQ);
        const float bb = bias[n];
#pragma unroll
        for (int mi = 0; mi < 2; ++mi) {
            const int rbase = m_tile + wm + mi * 32 + 4 * hi;
#pragma unroll
            for (int r = 0; r < 16; ++r) {
                const int row = rbase + (r & 3) + 8 * (r >> 2);
                out[(size_t)row * OUT_F + n] = sc * (float)acc[mi][ni][r] + bb;
            }
        }
    }
}

// ---------------------------------------------------------------------------
extern "C" void kernel_launch(void* const* d_in, const int* in_sizes, int n_in,
                              void* d_out, int out_size, void* d_ws, size_t ws_size,
                              hipStream_t stream) {
    const float* x      = (const float*)d_in[0];
    const float* W      = (const float*)d_in[1];
    const float* lA     = (const float*)d_in[2];
    const float* lB     = (const float*)d_in[3];
    const float* wscale = (const float*)d_in[4];
    const float* ascale = (const float*)d_in[5];
    const float* bias   = (const float*)d_in[6];
    float* out = (float*)d_out;

    const int M = in_sizes[0] / IN_F;          // 8192
    int8_t* qx = (int8_t*)d_ws;                             // M*K bytes
    int8_t* qw = qx + (size_t)M * IN_F;                     // N*K bytes

    qx_kernel<<<(in_sizes[0] / 8 + 255) / 256, 256, 0, stream>>>(x, ascale, qx);
    qw_kernel<<<dim3(IN_F / 1024, OUT_F / 64), 256, 0, stream>>>(W, lA, lB, wscale, qw);
    gemm_i8_kernel<<<dim3((M / BM) * (OUT_F / BN)), 256, 0, stream>>>(
        qx, qw, wscale, ascale, bias, out);
}